// Round 1
// baseline (1892.636 us; speedup 1.0000x reference)
//
#include <hip/hip_runtime.h>
#include <math.h>

#define RANKC   2
#define ALPHA_F 0.1f
#define BSCALE  (500.0f/512.0f)
#define HIDDEN  512
#define INPUT   8
#define NUM_MIX 2
#define BATCH   64
#define SEQ     2048
#define DD      12
#define KOUT    10
#define TTILE   16
#define HP      (HIDDEN+1)   // padded stride to avoid 512-stride LDS bank conflicts

__global__ __launch_bounds__(HIDDEN) void fsm_rnn_kernel(
    const float* __restrict__ x,          // (B, SEQ, INPUT)
    const float* __restrict__ means,      // (NUM_MIX, DD)
    const float* __restrict__ scale_tril, // (NUM_MIX, DD, DD)
    const float* __restrict__ mixw,       // (NUM_MIX,)
    const float* __restrict__ seeds,      // (4, HIDDEN, DD)
    const int*   __restrict__ cur_seeds,  // (B,)
    float*       __restrict__ out)        // (B, SEQ, KOUT)
{
    __shared__ union {
        float SL[HIDDEN*KOUT];       // span matrix S (setup only)
        float Hbuf[TTILE*HP];        // hidden history (scan phase)
    } u;
    __shared__ float  Plds[KOUT*HP]; // pinv rows
    __shared__ double Leff[DD*DD];
    __shared__ double meansw[DD];
    __shared__ double Gd[KOUT*KOUT];
    __shared__ double Gi[KOUT*KOUT];
    __shared__ float  xs[TTILE*INPUT];
    __shared__ float  red[2][8][2];

    const int tid = threadIdx.x;
    const int b   = blockIdx.x;
    const int s   = cur_seeds[b];
    const int h   = tid;

    // ---- mixture weights (w = clip/sum) ----
    double w0 = fmax((double)mixw[0], 1e-6);
    double w1 = fmax((double)mixw[1], 1e-6);
    double wsum = w0 + w1;
    w0 /= wsum; w1 /= wsum;

    // ---- effective (weighted, clamped-tril) L and weighted means ----
    if (tid < DD*DD) {
        int d = tid / DD, e = tid % DD;
        double acc = 0.0;
        #pragma unroll
        for (int i = 0; i < NUM_MIX; ++i) {
            float v = scale_tril[i*DD*DD + d*DD + e];
            float c;
            if (d > e)       c = v;
            else if (d == e) c = fabsf(v - 1e-12f) + 1e-12f;
            else             c = 0.0f;
            acc += (i == 0 ? w0 : w1) * (double)c;
        }
        Leff[tid] = acc;
    }
    if (tid < DD)
        meansw[tid] = w0 * (double)means[tid] + w1 * (double)means[DD + tid];
    if (tid < KOUT*KOUT)
        Gi[tid] = (tid / KOUT == tid % KOUT) ? 1.0 : 0.0;
    __syncthreads();

    // ---- comb[h,:] = Leff @ seeds[s,h,:] + meansw  (per-thread, double) ----
    double comb[DD];
    {
        const float* sh = &seeds[(s*HIDDEN + h)*DD];
        #pragma unroll
        for (int d = 0; d < DD; ++d) {
            double acc = meansw[d];
            for (int e = 0; e <= d; ++e)
                acc += Leff[d*DD + e] * (double)sh[e];
            comb[d] = acc;
        }
    }
    const float m0 = (float)comb[0], m1 = (float)comb[1];
    const float n0 = (float)comb[2], n1 = (float)comb[3];
    float Iv[INPUT];
    #pragma unroll
    for (int i = 0; i < INPUT; ++i) Iv[i] = (float)comb[4+i];

    // span S = [m | I]  (skip n columns 2,3)
    u.SL[h*KOUT + 0] = m0;
    u.SL[h*KOUT + 1] = m1;
    #pragma unroll
    for (int i = 0; i < INPUT; ++i) u.SL[h*KOUT + 2 + i] = Iv[i];
    __syncthreads();

    // ---- Gram matrix G = S^T S (double) ----
    if (tid < KOUT*KOUT) {
        int k = tid / KOUT, j = tid % KOUT;
        double g = 0.0;
        for (int hh = 0; hh < HIDDEN; ++hh)
            g += (double)u.SL[hh*KOUT + k] * (double)u.SL[hh*KOUT + j];
        Gd[tid] = g;
    }
    __syncthreads();

    // ---- invert G (Gauss-Jordan, partial pivoting, single thread) ----
    if (tid == 0) {
        for (int c = 0; c < KOUT; ++c) {
            int piv = c; double best = fabs(Gd[c*KOUT + c]);
            for (int r = c+1; r < KOUT; ++r) {
                double a = fabs(Gd[r*KOUT + c]);
                if (a > best) { best = a; piv = r; }
            }
            if (piv != c) {
                for (int j = 0; j < KOUT; ++j) {
                    double t0 = Gd[c*KOUT+j]; Gd[c*KOUT+j] = Gd[piv*KOUT+j]; Gd[piv*KOUT+j] = t0;
                    double t1 = Gi[c*KOUT+j]; Gi[c*KOUT+j] = Gi[piv*KOUT+j]; Gi[piv*KOUT+j] = t1;
                }
            }
            double inv = 1.0 / Gd[c*KOUT + c];
            for (int j = 0; j < KOUT; ++j) { Gd[c*KOUT+j] *= inv; Gi[c*KOUT+j] *= inv; }
            for (int r = 0; r < KOUT; ++r) {
                if (r == c) continue;
                double f = Gd[r*KOUT + c];
                if (f != 0.0) {
                    for (int j = 0; j < KOUT; ++j) {
                        Gd[r*KOUT+j] -= f * Gd[c*KOUT+j];
                        Gi[r*KOUT+j] -= f * Gi[c*KOUT+j];
                    }
                }
            }
        }
    }
    __syncthreads();

    // ---- P[k,h] = sum_j Ginv[k,j] * S[h,j] ----
    {
        float sl[KOUT];
        #pragma unroll
        for (int j = 0; j < KOUT; ++j) sl[j] = u.SL[h*KOUT + j];
        #pragma unroll
        for (int k = 0; k < KOUT; ++k) {
            double a = 0.0;
            #pragma unroll
            for (int j = 0; j < KOUT; ++j) a += Gi[k*KOUT + j] * (double)sl[j];
            Plds[k*HP + h] = (float)a;
        }
    }
    __syncthreads();   // SL dead from here; Hbuf may reuse the union

    // ---- sequential scan over SEQ, rank-2 J, fused Ix and output proj ----
    const int lane = tid & 63;
    const int wv   = tid >> 6;
    float hstate = 0.0f;
    const float* xb   = &x[(size_t)b * SEQ * INPUT];
    float*       outb = &out[(size_t)b * SEQ * KOUT];

    for (int t0 = 0; t0 < SEQ; t0 += TTILE) {
        if (tid < TTILE*INPUT) xs[tid] = xb[t0*INPUT + tid];
        __syncthreads();   // xs ready; previous projection complete

        for (int tt = 0; tt < TTILE; ++tt) {
            const int par = tt & 1;
            float th = tanhf(hstate);
            float p0 = n0 * th, p1 = n1 * th;
            #pragma unroll
            for (int mk = 32; mk >= 1; mk >>= 1) {
                p0 += __shfl_xor(p0, mk, 64);
                p1 += __shfl_xor(p1, mk, 64);
            }
            if (lane == 0) { red[par][wv][0] = p0; red[par][wv][1] = p1; }
            __syncthreads();
            float v0 = 0.f, v1 = 0.f;
            #pragma unroll
            for (int w = 0; w < 8; ++w) { v0 += red[par][w][0]; v1 += red[par][w][1]; }

            float ix = 0.f;
            #pragma unroll
            for (int i = 0; i < INPUT; ++i) ix = fmaf(Iv[i], xs[tt*INPUT + i], ix);

            float jth = BSCALE * fmaf(m0, v0, m1 * v1);
            float dh  = jth + ix - hstate;
            hstate = fmaf(ALPHA_F, dh, hstate);
            u.Hbuf[tt*HP + h] = hstate;
        }
        __syncthreads();   // Hbuf complete

        // out[t0+tt, k] = P[k,:] . h_t   (160 threads, 512-length dots)
        if (tid < TTILE*KOUT) {
            int tt = tid / KOUT, k = tid % KOUT;
            const float* Hrow = &u.Hbuf[tt*HP];
            const float* Prow = &Plds[k*HP];
            float acc = 0.f;
            #pragma unroll 8
            for (int hh = 0; hh < HIDDEN; ++hh)
                acc = fmaf(Prow[hh], Hrow[hh], acc);
            outb[(t0 + tt)*KOUT + k] = acc;
        }
    }
}

extern "C" void kernel_launch(void* const* d_in, const int* in_sizes, int n_in,
                              void* d_out, int out_size, void* d_ws, size_t ws_size,
                              hipStream_t stream) {
    const float* x          = (const float*)d_in[0];
    const float* means      = (const float*)d_in[1];
    const float* scale_tril = (const float*)d_in[2];
    const float* mixw       = (const float*)d_in[3];
    const float* seeds      = (const float*)d_in[4];
    const int*   cur_seeds  = (const int*)d_in[5];
    float* out = (float*)d_out;

    fsm_rnn_kernel<<<BATCH, HIDDEN, 0, stream>>>(
        x, means, scale_tril, mixw, seeds, cur_seeds, out);
}

// Round 2
// 891.613 us; speedup vs baseline: 2.1227x; 2.1227x over previous
//
#include <hip/hip_runtime.h>
#include <math.h>

#define HIDDEN  512
#define INPUT   8
#define NUM_MIX 2
#define BATCH   64
#define SEQ     2048
#define DD      12
#define KOUT    10
#define TTILE   8
#define NTILES  (SEQ/TTILE)

#define ALPHA_C   0.1
#define BSCALE_C  (500.0/512.0)

// DPP-based full-wave (64 lane) sum -> uniform scalar in all lanes.
template<int CTRL>
__device__ __forceinline__ float dpp_add(float x) {
    int y = __builtin_amdgcn_update_dpp(0, __float_as_int(x), CTRL, 0xF, 0xF, true);
    return x + __int_as_float(y);
}
__device__ __forceinline__ float wave_allsum(float x) {
    x = dpp_add<0x111>(x);   // row_shr:1
    x = dpp_add<0x112>(x);   // row_shr:2
    x = dpp_add<0x114>(x);   // row_shr:4
    x = dpp_add<0x118>(x);   // row_shr:8  -> lanes 15/31/47/63 hold row sums
    x = dpp_add<0x142>(x);   // row_bcast:15
    x = dpp_add<0x143>(x);   // row_bcast:31 -> lane 63 holds full sum
    return __int_as_float(__builtin_amdgcn_readlane(__float_as_int(x), 63));
}

// tanh(x) = 1 - 2/(exp2(2*log2(e)*x)+1)   (3 VALU ops; exact at +/-inf)
__device__ __forceinline__ float ftanh(float x) {
    float e = __builtin_amdgcn_exp2f(x * 2.885390081777927f);
    return fmaf(-2.0f, __builtin_amdgcn_rcpf(e + 1.0f), 1.0f);
}

__global__ __launch_bounds__(256) void fsm_rnn_kernel(
    const float* __restrict__ x,          // (B, SEQ, INPUT)
    const float* __restrict__ means,      // (NUM_MIX, DD)
    const float* __restrict__ scale_tril, // (NUM_MIX, DD, DD)
    const float* __restrict__ mixw,       // (NUM_MIX,)
    const float* __restrict__ seeds,      // (4, HIDDEN, DD)
    const int*   __restrict__ cur_seeds,  // (B,)
    float*       __restrict__ out)        // (B, SEQ, KOUT)
{
    __shared__ __align__(16) float IxB[2][TTILE][HIDDEN]; // alpha * I x tiles (dbuf)
    __shared__ __align__(16) float xsB[2][TTILE*INPUT];   // x tiles (dbuf)
    __shared__ __align__(16) float IvL[HIDDEN][INPUT];    // alpha * I rows
    __shared__ float PM0[HIDDEN], PM1[HIDDEN], N0[HIDDEN], N1[HIDDEN];
    __shared__ double Leff[DD*DD];
    __shared__ double meansw[DD];

    const int tid  = threadIdx.x;
    const int lane = tid & 63;
    const int wid  = tid >> 6;
    const int b    = blockIdx.x;
    const int s    = cur_seeds[b];
    const float* xb = x + (size_t)b * SEQ * INPUT;
    float* outb = out + (size_t)b * SEQ * KOUT;

    // ---- mixture weights ----
    double w0 = fmax((double)mixw[0], 1e-6);
    double w1 = fmax((double)mixw[1], 1e-6);
    double wsum = w0 + w1; w0 /= wsum; w1 /= wsum;

    // ---- weighted clamped-tril L, weighted means ----
    if (tid < DD*DD) {
        int d = tid / DD, e = tid % DD;
        double acc = 0.0;
        #pragma unroll
        for (int i = 0; i < NUM_MIX; ++i) {
            float v = scale_tril[i*DD*DD + d*DD + e];
            float c = (d > e) ? v : (d == e ? fabsf(v - 1e-12f) + 1e-12f : 0.0f);
            acc += (i == 0 ? w0 : w1) * (double)c;
        }
        Leff[tid] = acc;
    }
    if (tid < DD)
        meansw[tid] = w0 * (double)means[tid] + w1 * (double)means[DD + tid];
    if (tid < 2*TTILE*INPUT)                       // stage x tiles 0 and 1
        ((float*)xsB)[tid] = xb[tid];
    __syncthreads();

    // ---- per-h params: comb = Leff @ seeds[s,h,:] + meansw (double) ----
    #pragma unroll
    for (int rr = 0; rr < 2; ++rr) {
        int h = tid + rr*256;
        const float* sh = &seeds[(s*HIDDEN + h)*DD];
        double comb[DD];
        #pragma unroll
        for (int d = 0; d < DD; ++d) {
            double acc = meansw[d];
            for (int e = 0; e <= d; ++e)
                acc += Leff[d*DD + e] * (double)sh[e];
            comb[d] = acc;
        }
        PM0[h] = (float)(ALPHA_C * BSCALE_C * comb[0]);   // alpha*B*m0
        PM1[h] = (float)(ALPHA_C * BSCALE_C * comb[1]);   // alpha*B*m1
        N0[h]  = (float)comb[2];
        N1[h]  = (float)comb[3];
        #pragma unroll
        for (int i = 0; i < INPUT; ++i)
            IvL[h][i] = (float)(ALPHA_C * comb[4 + i]);   // alpha*I[h,i]
    }
    __syncthreads();

    // ---- persistent per-role state ----
    float am0[8], am1[8], nn0[8], nn1[8], hst[8];
    float4 IvA[3], IvC[3];
    float zf = 0.0f, w0s = 0.0f, w1s = 0.0f;
    const int pid = (wid - 1)*64 + lane;   // producer id 0..191
    const int zi  = lane - 56;

    if (wid == 0) {
        #pragma unroll
        for (int j = 0; j < 8; ++j) {
            int h = lane*8 + j;
            am0[j] = PM0[h]; am1[j] = PM1[h];
            nn0[j] = N0[h];  nn1[j] = N1[h];
            hst[j] = 0.0f;
        }
    } else {
        int q = 0;
        for (int h = pid; h < HIDDEN; h += 192, ++q) {
            IvA[q] = *(const float4*)&IvL[h][0];
            IvC[q] = *(const float4*)&IvL[h][4];
        }
    }

    // producer phase: fill IxB[tg&1] for tile tg from xsB[tg&1]; z-filter outputs
    auto produce = [&](int tg) {
        const int pb = tg & 1;
        const float* xs = xsB[pb];
        #pragma unroll
        for (int tt = 0; tt < TTILE; ++tt) {
            float4 xa = *(const float4*)&xs[tt*INPUT];
            float4 xc = *(const float4*)&xs[tt*INPUT + 4];
            int q = 0;
            for (int h = pid; h < HIDDEN; h += 192, ++q) {
                float v =      IvA[q].x * xa.x;
                v = fmaf(IvA[q].y, xa.y, v);
                v = fmaf(IvA[q].z, xa.z, v);
                v = fmaf(IvA[q].w, xa.w, v);
                v = fmaf(IvC[q].x, xc.x, v);
                v = fmaf(IvC[q].y, xc.y, v);
                v = fmaf(IvC[q].z, xc.z, v);
                v = fmaf(IvC[q].w, xc.w, v);
                IxB[pb][tt][h] = v;
            }
        }
        if (wid == 1 && lane >= 56) {   // out[:, 2:10] = EMA filter of x
            #pragma unroll
            for (int tt = 0; tt < TTILE; ++tt) {
                zf = fmaf(0.9f, zf, 0.1f * xs[tt*INPUT + zi]);
                outb[(tg*TTILE + tt)*KOUT + 2 + zi] = zf;
            }
        }
    };

    if (wid != 0) produce(0);   // prologue: tile 0
    __syncthreads();

    for (int T = 0; T < NTILES; ++T) {
        if (wid == 0) {
            // ---- consumer: 8 scan steps, zero barriers, DPP reduction ----
            const float* myix = &IxB[T & 1][0][lane*8];
            float4 ca = *(const float4*)myix;
            float4 cb = *(const float4*)(myix + 4);
            #pragma unroll
            for (int tt = 0; tt < TTILE; ++tt) {
                float4 na, nb;
                if (tt < TTILE-1) {   // prefetch next step's ix early
                    na = *(const float4*)(myix + (tt+1)*HIDDEN);
                    nb = *(const float4*)(myix + (tt+1)*HIDDEN + 4);
                }
                float th[8];
                #pragma unroll
                for (int j = 0; j < 8; ++j) th[j] = ftanh(hst[j]);
                float p0 = th[0]*nn0[0], p1 = th[0]*nn1[0];
                #pragma unroll
                for (int j = 1; j < 8; ++j) {
                    p0 = fmaf(th[j], nn0[j], p0);
                    p1 = fmaf(th[j], nn1[j], p1);
                }
                float v0 = wave_allsum(p0);
                float v1 = wave_allsum(p1);
                float cax[8] = {ca.x, ca.y, ca.z, ca.w, cb.x, cb.y, cb.z, cb.w};
                #pragma unroll
                for (int j = 0; j < 8; ++j)
                    hst[j] = fmaf(0.9f, hst[j],
                              fmaf(am0[j], v0, fmaf(am1[j], v1, cax[j])));
                w0s = fmaf(0.9f, w0s, 0.09765625f * v0);  // alpha*BSCALE = 50/512
                w1s = fmaf(0.9f, w1s, 0.09765625f * v1);
                if (lane < 2)
                    outb[(T*TTILE + tt)*KOUT + lane] = (lane == 0) ? w0s : w1s;
                ca = na; cb = nb;
            }
        } else {
            if (T + 1 < NTILES) produce(T + 1);
            if (T + 2 < NTILES && wid == 2)    // stage x tile T+2
                ((float*)xsB[T & 1])[lane] = xb[(T + 2)*(TTILE*INPUT) + lane];
        }
        __syncthreads();
    }
}

extern "C" void kernel_launch(void* const* d_in, const int* in_sizes, int n_in,
                              void* d_out, int out_size, void* d_ws, size_t ws_size,
                              hipStream_t stream) {
    (void)d_ws; (void)ws_size;
    const float* x          = (const float*)d_in[0];
    const float* means      = (const float*)d_in[1];
    const float* scale_tril = (const float*)d_in[2];
    const float* mixw       = (const float*)d_in[3];
    const float* seeds      = (const float*)d_in[4];
    const int*   cur_seeds  = (const int*)d_in[5];
    float* out = (float*)d_out;

    fsm_rnn_kernel<<<BATCH, 256, 0, stream>>>(
        x, means, scale_tril, mixw, seeds, cur_seeds, out);
}

// Round 3
// 767.348 us; speedup vs baseline: 2.4665x; 1.1619x over previous
//
#include <hip/hip_runtime.h>
#include <math.h>

#define HIDDEN  512
#define INPUT   8
#define NUM_MIX 2
#define BATCH   64
#define SEQ     2048
#define DD      12
#define KOUT    10
#define TTILE   16
#define NTILES  (SEQ/TTILE)

// h-state is kept pre-scaled by 2*log2(e) so tanh needs no per-step multiply:
// tanh(h) = 1 - 2*rcp(exp2(h_s)+1),  h_s = 2*log2(e)*h
#define SCALE_F 2.8853900817779268f
#define AB_F    0.09765625f   /* alpha*BASE_SCALE/HIDDEN = 50/512 (unscaled, for w-EMA) */

typedef float v2f  __attribute__((ext_vector_type(2)));
typedef float f4v  __attribute__((ext_vector_type(4)));

__device__ __forceinline__ v2f pk_fma(v2f a, v2f b, v2f c) {
    return __builtin_elementwise_fma(a, b, c);
}

template<int CTRL>
__device__ __forceinline__ float dpp_add(float x) {
    int y = __builtin_amdgcn_update_dpp(0, __float_as_int(x), CTRL, 0xF, 0xF, true);
    return x + __int_as_float(y);
}
__device__ __forceinline__ float wave_allsum(float x) {
    x = dpp_add<0x111>(x);   // row_shr:1
    x = dpp_add<0x112>(x);   // row_shr:2
    x = dpp_add<0x114>(x);   // row_shr:4
    x = dpp_add<0x118>(x);   // row_shr:8
    x = dpp_add<0x142>(x);   // row_bcast:15
    x = dpp_add<0x143>(x);   // row_bcast:31
    return __int_as_float(__builtin_amdgcn_readlane(__float_as_int(x), 63));
}

__global__ __launch_bounds__(256) void fsm_rnn_kernel(
    const float* __restrict__ x,          // (B, SEQ, INPUT)
    const float* __restrict__ means,      // (NUM_MIX, DD)
    const float* __restrict__ scale_tril, // (NUM_MIX, DD, DD)
    const float* __restrict__ mixw,       // (NUM_MIX,)
    const float* __restrict__ seeds,      // (4, HIDDEN, DD)
    const int*   __restrict__ cur_seeds,  // (B,)
    float*       __restrict__ out)        // (B, SEQ, KOUT)
{
    __shared__ __align__(16) float IxB[2][TTILE][HIDDEN];   // 64KB scaled alpha*I*x
    __shared__ __align__(16) float xsB[2][TTILE*INPUT];     // 1KB
    __shared__ __align__(16) float IvL[HIDDEN][INPUT];      // 16KB scaled alpha*I
    __shared__ float PM0[HIDDEN], PM1[HIDDEN], N0[HIDDEN], N1[HIDDEN]; // 8KB
    __shared__ __align__(8) float vring[2][TTILE][64][2];   // 16KB (v0,v1) per step
    __shared__ double Leff[DD*DD];
    __shared__ double meansw[DD];

    const int tid  = threadIdx.x;
    const int lane = tid & 63;
    const int wid  = tid >> 6;
    const int b    = blockIdx.x;
    const int s    = cur_seeds[b];
    const float* xb = x + (size_t)b * SEQ * INPUT;
    float* outb = out + (size_t)b * SEQ * KOUT;

    // ---- mixture weights ----
    double w0 = fmax((double)mixw[0], 1e-6);
    double w1 = fmax((double)mixw[1], 1e-6);
    double wsum = w0 + w1; w0 /= wsum; w1 /= wsum;

    // ---- weighted clamped-tril L, weighted means ----
    if (tid < DD*DD) {
        int d = tid / DD, e = tid % DD;
        double acc = 0.0;
        #pragma unroll
        for (int i = 0; i < NUM_MIX; ++i) {
            float v = scale_tril[i*DD*DD + d*DD + e];
            float c = (d > e) ? v : (d == e ? fabsf(v - 1e-12f) + 1e-12f : 0.0f);
            acc += (i == 0 ? w0 : w1) * (double)c;
        }
        Leff[tid] = acc;
    }
    if (tid < DD)
        meansw[tid] = w0 * (double)means[tid] + w1 * (double)means[DD + tid];
    if (tid < 2*TTILE*INPUT)                       // stage x tiles 0 and 1
        ((float*)xsB)[tid] = xb[tid];
    __syncthreads();

    // ---- per-h params (double precision), stored pre-scaled ----
    #pragma unroll
    for (int rr = 0; rr < 2; ++rr) {
        int h = tid + rr*256;
        const float* sh = &seeds[(s*HIDDEN + h)*DD];
        double comb[DD];
        #pragma unroll
        for (int d = 0; d < DD; ++d) {
            double acc = meansw[d];
            for (int e = 0; e <= d; ++e)
                acc += Leff[d*DD + e] * (double)sh[e];
            comb[d] = acc;
        }
        PM0[h] = (float)((double)SCALE_F * (double)AB_F * comb[0]); // scaled alpha*B*m0
        PM1[h] = (float)((double)SCALE_F * (double)AB_F * comb[1]);
        N0[h]  = (float)comb[2];                                    // unscaled n
        N1[h]  = (float)comb[3];
        #pragma unroll
        for (int i = 0; i < INPUT; ++i)
            IvL[h][i] = (float)((double)SCALE_F * 0.1 * comb[4 + i]); // scaled alpha*I
    }
    __syncthreads();

    // ---- persistent per-role state ----
    v2f AM0[4], AM1[4], NN0[4], NN1[4], H[4];
    f4v IvA[3], IvC[3];
    float zf = 0.0f, wst = 0.0f;
    const int pid = (wid - 1)*64 + lane;   // producer id 0..191
    const int zi  = lane - 56;

    if (wid == 0) {
        #pragma unroll
        for (int q = 0; q < 4; ++q) {
            int hh = lane*8 + 2*q;
            AM0[q] = (v2f){PM0[hh], PM0[hh+1]};
            AM1[q] = (v2f){PM1[hh], PM1[hh+1]};
            NN0[q] = (v2f){N0[hh],  N0[hh+1]};
            NN1[q] = (v2f){N1[hh],  N1[hh+1]};
            H[q]   = (v2f){0.0f, 0.0f};
        }
    } else {
        int q = 0;
        for (int h = pid; h < HIDDEN; h += 192, ++q) {
            IvA[q] = *(const f4v*)&IvL[h][0];
            IvC[q] = *(const f4v*)&IvL[h][4];
        }
    }

    // producer: fill IxB for tile tg from xsB; wave1 lanes 56-63 emit z-filter
    auto produce = [&](int tg) {
        const int pb = tg & 1;
        const float* xs = xsB[pb];
        for (int tt = 0; tt < TTILE; ++tt) {
            f4v xa = *(const f4v*)&xs[tt*INPUT];
            f4v xc = *(const f4v*)&xs[tt*INPUT + 4];
            int q = 0;
            for (int h = pid; h < HIDDEN; h += 192, ++q) {
                float v =      IvA[q].x * xa.x;
                v = fmaf(IvA[q].y, xa.y, v);
                v = fmaf(IvA[q].z, xa.z, v);
                v = fmaf(IvA[q].w, xa.w, v);
                v = fmaf(IvC[q].x, xc.x, v);
                v = fmaf(IvC[q].y, xc.y, v);
                v = fmaf(IvC[q].z, xc.z, v);
                v = fmaf(IvC[q].w, xc.w, v);
                IxB[pb][tt][h] = v;
            }
        }
        if (wid == 1 && lane >= 56) {   // out[:, 2:10] = EMA of x
            #pragma unroll 4
            for (int tt = 0; tt < TTILE; ++tt) {
                zf = fmaf(0.9f, zf, 0.1f * xs[tt*INPUT + zi]);
                outb[(tg*TTILE + tt)*KOUT + 2 + zi] = zf;
            }
        }
    };

    // helper: w-EMA for columns 0,1 of a finished tile (lanes 54,55 of wave 1)
    auto process_w = [&](int tile) {
        if (lane == 54 || lane == 55) {
            const int widx = lane & 1;
            const float* vr = &vring[tile & 1][0][0][widx];
            for (int tt = 0; tt < TTILE; ++tt) {
                wst = fmaf(0.9f, wst, AB_F * vr[tt*128]);
                outb[(tile*TTILE + tt)*KOUT + widx] = wst;
            }
        }
    };

    if (wid != 0) produce(0);   // prologue
    __syncthreads();

    for (int T = 0; T < NTILES; ++T) {
        if (wid == 0) {
            // ---- consumer: 16 steps, packed fp32, zero global stores ----
            const float* ixp   = &IxB[T & 1][0][lane*8];
            float*       ringp = &vring[T & 1][0][lane][0];
            #pragma unroll
            for (int tt = 0; tt < TTILE; ++tt) {
                const f4v* cf = (const f4v*)(ixp + tt*HIDDEN);
                f4v f0 = cf[0], f1 = cf[1];
                v2f c0 = {f0.x, f0.y}, c1 = {f0.z, f0.w};
                v2f c2 = {f1.x, f1.y}, c3 = {f1.z, f1.w};

                v2f th[4];
                #pragma unroll
                for (int q = 0; q < 4; ++q) {
                    v2f E = { __builtin_amdgcn_exp2f(H[q].x),
                              __builtin_amdgcn_exp2f(H[q].y) };
                    v2f A = E + 1.0f;
                    v2f Bv = { __builtin_amdgcn_rcpf(A.x),
                               __builtin_amdgcn_rcpf(A.y) };
                    const v2f m2 = {-2.0f, -2.0f}, one = {1.0f, 1.0f};
                    th[q] = pk_fma(m2, Bv, one);   // tanh, exact at +/-inf
                }
                v2f a0 = th[0]*NN0[0];
                a0 = pk_fma(th[1], NN0[1], a0);
                a0 = pk_fma(th[2], NN0[2], a0);
                a0 = pk_fma(th[3], NN0[3], a0);
                v2f a1 = th[0]*NN1[0];
                a1 = pk_fma(th[1], NN1[1], a1);
                a1 = pk_fma(th[2], NN1[2], a1);
                a1 = pk_fma(th[3], NN1[3], a1);
                float p0 = a0.x + a0.y;
                float p1 = a1.x + a1.y;

                float v0 = wave_allsum(p0);
                float v1 = wave_allsum(p1);

                const v2f nine = {0.9f, 0.9f};
                v2f hc0 = pk_fma(nine, H[0], c0);   // scheduled into DPP shadow
                v2f hc1 = pk_fma(nine, H[1], c1);
                v2f hc2 = pk_fma(nine, H[2], c2);
                v2f hc3 = pk_fma(nine, H[3], c3);

                v2f v0v = {v0, v0}, v1v = {v1, v1};
                H[0] = pk_fma(AM0[0], v0v, pk_fma(AM1[0], v1v, hc0));
                H[1] = pk_fma(AM0[1], v0v, pk_fma(AM1[1], v1v, hc1));
                H[2] = pk_fma(AM0[2], v0v, pk_fma(AM1[2], v1v, hc2));
                H[3] = pk_fma(AM0[3], v0v, pk_fma(AM1[3], v1v, hc3));

                *(v2f*)(ringp + tt*128) = (v2f){v0, v1};
            }
        } else {
            if (T + 1 < NTILES) produce(T + 1);
            if (wid == 2 && T + 2 < NTILES) {      // stage x tile T+2
                const int base = (T + 2)*(TTILE*INPUT);
                xsB[T & 1][lane]      = xb[base + lane];
                xsB[T & 1][lane + 64] = xb[base + lane + 64];
            }
            if (wid == 1 && T >= 1) process_w(T - 1);
        }
        __syncthreads();
    }
    if (wid == 1) process_w(NTILES - 1);   // ring[last] visible after final barrier
}

extern "C" void kernel_launch(void* const* d_in, const int* in_sizes, int n_in,
                              void* d_out, int out_size, void* d_ws, size_t ws_size,
                              hipStream_t stream) {
    (void)d_ws; (void)ws_size;
    const float* x          = (const float*)d_in[0];
    const float* means      = (const float*)d_in[1];
    const float* scale_tril = (const float*)d_in[2];
    const float* mixw       = (const float*)d_in[3];
    const float* seeds      = (const float*)d_in[4];
    const int*   cur_seeds  = (const int*)d_in[5];
    float* out = (float*)d_out;

    fsm_rnn_kernel<<<BATCH, 256, 0, stream>>>(
        x, means, scale_tril, mixw, seeds, cur_seeds, out);
}

// Round 4
// 519.802 us; speedup vs baseline: 3.6411x; 1.4762x over previous
//
#include <hip/hip_runtime.h>
#include <math.h>

#define HIDDEN  512
#define INPUT   8
#define NUM_MIX 2
#define BATCH   64
#define SEQ     2048
#define DD      12
#define KOUT    10
#define TTILE   16
#define NTILES  (SEQ/TTILE)

// h-state kept pre-scaled by 2*log2(e): tanh(h) = 1 - 2*rcp(exp2(h_s)+1)
#define SCALE_F 2.8853900817779268
#define AB_F    0.09765625f   /* alpha*BASE_SCALE/HIDDEN = 50/512 */

typedef float v2f __attribute__((ext_vector_type(2)));
typedef float f4v __attribute__((ext_vector_type(4)));

__device__ __forceinline__ v2f pk_fma(v2f a, v2f b, v2f c) {
    return __builtin_elementwise_fma(a, b, c);
}

template<int CTRL>
__device__ __forceinline__ float dpp_add(float x) {
    int y = __builtin_amdgcn_update_dpp(0, __float_as_int(x), CTRL, 0xF, 0xF, true);
    return x + __int_as_float(y);
}
__device__ __forceinline__ float wave_allsum(float x) {
    x = dpp_add<0x111>(x);   // row_shr:1
    x = dpp_add<0x112>(x);   // row_shr:2
    x = dpp_add<0x114>(x);   // row_shr:4
    x = dpp_add<0x118>(x);   // row_shr:8
    x = dpp_add<0x142>(x);   // row_bcast:15
    x = dpp_add<0x143>(x);   // row_bcast:31
    return __int_as_float(__builtin_amdgcn_readlane(__float_as_int(x), 63));
}

__global__ __launch_bounds__(256) void fsm_rnn_kernel(
    const float* __restrict__ x,          // (B, SEQ, INPUT)
    const float* __restrict__ means,      // (NUM_MIX, DD)
    const float* __restrict__ scale_tril, // (NUM_MIX, DD, DD)
    const float* __restrict__ mixw,       // (NUM_MIX,)
    const float* __restrict__ seeds,      // (4, HIDDEN, DD)
    const int*   __restrict__ cur_seeds,  // (B,)
    float*       __restrict__ out)        // (B, SEQ, KOUT)
{
    __shared__ __align__(16) float IxB[2][TTILE][HIDDEN];   // 64KB scaled alpha*I*x
    __shared__ __align__(16) float xsB[2][TTILE*INPUT];     // 1KB raw x tiles
    __shared__ __align__(16) float IvL[HIDDEN][INPUT];      // 16KB scaled alpha*I
    __shared__ float PM0[HIDDEN], PM1[HIDDEN], N0[HIDDEN], N1[HIDDEN]; // 8KB
    __shared__ __align__(8) float vring[2][TTILE][2];       // (v0,v1) per step
    __shared__ double Leff[DD*DD];
    __shared__ double meansw[DD];

    const int tid  = threadIdx.x;
    const int lane = tid & 63;
    const int wid  = tid >> 6;
    const int b    = blockIdx.x;
    const int s    = cur_seeds[b];
    const float* xb = x + (size_t)b * SEQ * INPUT;
    float* outb = out + (size_t)b * SEQ * KOUT;

    // ---- mixture weights ----
    double w0 = fmax((double)mixw[0], 1e-6);
    double w1 = fmax((double)mixw[1], 1e-6);
    double wsum = w0 + w1; w0 /= wsum; w1 /= wsum;

    // ---- weighted clamped-tril L, weighted means ----
    if (tid < DD*DD) {
        int d = tid / DD, e = tid % DD;
        double acc = 0.0;
        #pragma unroll
        for (int i = 0; i < NUM_MIX; ++i) {
            float v = scale_tril[i*DD*DD + d*DD + e];
            float c = (d > e) ? v : (d == e ? fabsf(v - 1e-12f) + 1e-12f : 0.0f);
            acc += (i == 0 ? w0 : w1) * (double)c;
        }
        Leff[tid] = acc;
    }
    if (tid < DD)
        meansw[tid] = w0 * (double)means[tid] + w1 * (double)means[DD + tid];
    if (tid < 2*TTILE*INPUT)
        ((float*)xsB)[tid] = xb[tid];          // stage x tiles 0,1
    __syncthreads();

    // ---- per-h params (double), stored pre-scaled ----
    #pragma unroll
    for (int rr = 0; rr < 2; ++rr) {
        int h = tid + rr*256;
        const float* sh = &seeds[(s*HIDDEN + h)*DD];
        double comb[DD];
        #pragma unroll
        for (int d = 0; d < DD; ++d) {
            double acc = meansw[d];
            for (int e = 0; e <= d; ++e)
                acc += Leff[d*DD + e] * (double)sh[e];
            comb[d] = acc;
        }
        PM0[h] = (float)(SCALE_F * (double)AB_F * comb[0]);
        PM1[h] = (float)(SCALE_F * (double)AB_F * comb[1]);
        N0[h]  = (float)comb[2];
        N1[h]  = (float)comb[3];
        #pragma unroll
        for (int i = 0; i < INPUT; ++i)
            IvL[h][i] = (float)(SCALE_F * 0.1 * comb[4 + i]);
    }
    __syncthreads();

    // ---- persistent per-role state ----
    v2f AM0[4], AM1[4], NN0v[4], NN1v[4], H[4];
    f4v IvA[3], IvC[3];
    float zf = 0.0f, wst = 0.0f;
    const int pid = (wid - 1)*64 + lane;   // producer id 0..191
    const int zi  = lane - 56;

    if (wid == 0) {
        // consumer owns h = lane + 64*j, paired (2q, 2q+1)
        #pragma unroll
        for (int q = 0; q < 4; ++q) {
            int ha = lane + 64*(2*q), hb = lane + 64*(2*q + 1);
            AM0[q]  = (v2f){PM0[ha], PM0[hb]};
            AM1[q]  = (v2f){PM1[ha], PM1[hb]};
            NN0v[q] = (v2f){N0[ha],  N0[hb]};
            NN1v[q] = (v2f){N1[ha],  N1[hb]};
            H[q]    = (v2f){0.0f, 0.0f};
        }
    } else {
        #pragma unroll
        for (int q = 0; q < 3; ++q) {          // compile-time indices — no spill
            int h = pid + 192*q;
            if (h < HIDDEN) {
                IvA[q] = *(const f4v*)&IvL[h][0];
                IvC[q] = *(const f4v*)&IvL[h][4];
            }
        }
    }

    // producer: fill IxB tile tg; wave1 lanes 56-63 emit the z-filter outputs
    auto produce = [&](int tg) {
        const int pb = tg & 1;
        const float* xs = xsB[pb];
        for (int tt = 0; tt < TTILE; ++tt) {
            f4v xa = *(const f4v*)&xs[tt*INPUT];
            f4v xc = *(const f4v*)&xs[tt*INPUT + 4];
            #pragma unroll
            for (int q = 0; q < 3; ++q) {
                int h = pid + 192*q;
                if (h < HIDDEN) {
                    float v =      IvA[q].x * xa.x;
                    v = fmaf(IvA[q].y, xa.y, v);
                    v = fmaf(IvA[q].z, xa.z, v);
                    v = fmaf(IvA[q].w, xa.w, v);
                    v = fmaf(IvC[q].x, xc.x, v);
                    v = fmaf(IvC[q].y, xc.y, v);
                    v = fmaf(IvC[q].z, xc.z, v);
                    v = fmaf(IvC[q].w, xc.w, v);
                    IxB[pb][tt][h] = v;
                }
            }
        }
        if (wid == 1 && lane >= 56) {
            #pragma unroll 4
            for (int tt = 0; tt < TTILE; ++tt) {
                zf = fmaf(0.9f, zf, 0.1f * xs[tt*INPUT + zi]);
                outb[(tg*TTILE + tt)*KOUT + 2 + zi] = zf;
            }
        }
    };

    // w-EMA for columns 0,1 of a finished tile (lanes 54,55 of wave 1)
    auto process_w = [&](int tile) {
        if (lane == 54 || lane == 55) {
            const int widx = lane & 1;
            for (int tt = 0; tt < TTILE; ++tt) {
                wst = fmaf(0.9f, wst, AB_F * vring[tile & 1][tt][widx]);
                outb[(tile*TTILE + tt)*KOUT + widx] = wst;
            }
        }
    };

    if (wid != 0) produce(0);
    __syncthreads();

    for (int T = 0; T < NTILES; ++T) {
        if (wid == 0) {
            const int pb = T & 1;
            float cc[8], cn[8];
            #pragma unroll
            for (int j = 0; j < 8; ++j) cc[j] = IxB[pb][0][lane + 64*j];
            #pragma unroll
            for (int tt = 0; tt < TTILE; ++tt) {
                if (tt < TTILE-1) {            // prefetch next step (conflict-free)
                    #pragma unroll
                    for (int j = 0; j < 8; ++j)
                        cn[j] = IxB[pb][tt+1][lane + 64*j];
                }
                // tanh: scalar transcendentals, packed arithmetic
                v2f TH[4];
                #pragma unroll
                for (int q = 0; q < 4; ++q) {
                    v2f E;
                    E.x = __builtin_amdgcn_exp2f(H[q].x);
                    E.y = __builtin_amdgcn_exp2f(H[q].y);
                    v2f A = E + 1.0f;
                    v2f R;
                    R.x = __builtin_amdgcn_rcpf(A.x);
                    R.y = __builtin_amdgcn_rcpf(A.y);
                    const v2f m2 = {-2.0f, -2.0f}, one = {1.0f, 1.0f};
                    TH[q] = pk_fma(m2, R, one);
                }
                v2f s0 = TH[0]*NN0v[0];
                s0 = pk_fma(TH[1], NN0v[1], s0);
                s0 = pk_fma(TH[2], NN0v[2], s0);
                s0 = pk_fma(TH[3], NN0v[3], s0);
                v2f s1 = TH[0]*NN1v[0];
                s1 = pk_fma(TH[1], NN1v[1], s1);
                s1 = pk_fma(TH[2], NN1v[2], s1);
                s1 = pk_fma(TH[3], NN1v[3], s1);
                float p0 = s0.x + s0.y;
                float p1 = s1.x + s1.y;

                float v0 = wave_allsum(p0);
                float v1 = wave_allsum(p1);

                const v2f nine = {0.9f, 0.9f};
                v2f hc0 = pk_fma(nine, H[0], (v2f){cc[0], cc[1]});
                v2f hc1 = pk_fma(nine, H[1], (v2f){cc[2], cc[3]});
                v2f hc2 = pk_fma(nine, H[2], (v2f){cc[4], cc[5]});
                v2f hc3 = pk_fma(nine, H[3], (v2f){cc[6], cc[7]});

                v2f v0v = {v0, v0}, v1v = {v1, v1};
                H[0] = pk_fma(AM0[0], v0v, pk_fma(AM1[0], v1v, hc0));
                H[1] = pk_fma(AM0[1], v0v, pk_fma(AM1[1], v1v, hc1));
                H[2] = pk_fma(AM0[2], v0v, pk_fma(AM1[2], v1v, hc2));
                H[3] = pk_fma(AM0[3], v0v, pk_fma(AM1[3], v1v, hc3));

                if (lane == 0)
                    *(v2f*)&vring[pb][tt][0] = (v2f){v0, v1};

                #pragma unroll
                for (int j = 0; j < 8; ++j) cc[j] = cn[j];
            }
        } else {
            if (T + 1 < NTILES) produce(T + 1);
            if (wid == 2 && T + 2 < NTILES) {
                const int base = (T + 2)*(TTILE*INPUT);
                xsB[T & 1][lane]      = xb[base + lane];
                xsB[T & 1][lane + 64] = xb[base + lane + 64];
            }
            if (wid == 1 && T >= 1) process_w(T - 1);
        }
        __syncthreads();
    }
    if (wid == 1) process_w(NTILES - 1);
}

extern "C" void kernel_launch(void* const* d_in, const int* in_sizes, int n_in,
                              void* d_out, int out_size, void* d_ws, size_t ws_size,
                              hipStream_t stream) {
    (void)d_ws; (void)ws_size;
    const float* x          = (const float*)d_in[0];
    const float* means      = (const float*)d_in[1];
    const float* scale_tril = (const float*)d_in[2];
    const float* mixw       = (const float*)d_in[3];
    const float* seeds      = (const float*)d_in[4];
    const int*   cur_seeds  = (const int*)d_in[5];
    float* out = (float*)d_out;

    fsm_rnn_kernel<<<BATCH, 256, 0, stream>>>(
        x, means, scale_tril, mixw, seeds, cur_seeds, out);
}